// Round 1
// baseline (785.523 us; speedup 1.0000x reference)
//
#include <hip/hip_runtime.h>

// ---------------------------------------------------------------------------
// Fused "adjacency attention":
//   out = beta*softmax(q k^T/8 + adj) @ v, with diagonal of the score matrix
//   overwritten by alpha before the PV matmul.
// Flash-style: per WG a 64-row q tile, loop over 64-wide kv tiles.
// adj (512 MiB, stream-once) dominates HBM traffic -> memory-bound design.
// ---------------------------------------------------------------------------

#define LOG2E 1.4426950408889634f

typedef __attribute__((ext_vector_type(8))) short  short8;   // 8 x bf16 frag
typedef __attribute__((ext_vector_type(4))) short  short4v;
typedef __attribute__((ext_vector_type(4))) float  float4v;

constexpr int NH    = 8;
constexpr int N     = 4096;
constexpr int D     = 64;
constexpr int BM    = 64;          // q rows per workgroup
constexpr int BN    = 64;          // kv per tile
constexpr int TILES = N / BN;      // 64
constexpr int LDK   = 80;          // padded LDS row stride (bf16 units), 160 B

__device__ __forceinline__ short f2bf(float f) {
    unsigned u = __builtin_bit_cast(unsigned, f);
    u = (u + 0x7fffu + ((u >> 16) & 1u)) >> 16;   // RNE truncate to bf16
    return (short)u;
}

__global__ __launch_bounds__(256, 2)
void attn_adj_kernel(const float* __restrict__ gq, const float* __restrict__ gk,
                     const float* __restrict__ gv, const float* __restrict__ gadj,
                     const float* __restrict__ galpha, const float* __restrict__ gbeta,
                     float* __restrict__ gout)
{
    __shared__ short qLds[BM * LDK];
    __shared__ short kBuf[2][BN * LDK];    // K tile, row-major [kv][d]
    __shared__ short vtBuf[2][D * LDK];    // V tile transposed [d][kv]
    __shared__ short pLds[BM * LDK];       // P (bf16), rows wave-private

    const int tid  = threadIdx.x;
    const int lane = tid & 63;
    const int wv   = tid >> 6;      // wave 0..3 -> q rows [16*wv, 16*wv+16)
    const int l15  = lane & 15;
    const int l4   = lane >> 4;     // 0..3

    // XCD swizzle: consecutive blocks go to different XCDs (bx % 8); make the
    // head index follow that so each XCD's resident WGs share one head's K/V.
    const int h  = blockIdx.x & 7;
    const int qt = blockIdx.x >> 3;      // 0..63
    const int q0 = qt * BM;

    // ---- staging maps (256 threads)
    const int srow   = tid >> 2;         // 0..63  (K / Q row)
    const int schunk = tid & 3;          // 16-float chunk
    const int vd     = (tid & 15) * 4;   // V: d base
    const int vkv    = (tid >> 4) * 4;   // V: kv base

    const float* qp = gq + ((size_t)h * N + q0 + srow) * D + schunk * 16;
    const float* kp = gk + ((size_t)h * N + srow) * D + schunk * 16;
    const float* vp = gv + ((size_t)h * N + vkv) * D + vd;

    const int rowl = 16 * wv + l4 * 4;   // local q row base for C-layout (+reg)

    // adj row pointers (C-layout: row = rowl+r, col = l15 + j*64 + ct*16)
    const float* abr0;
    {
        const float* ab = gadj + ((size_t)h * N + q0 + rowl) * N + l15;
        abr0 = ab;
    }
    const float* abr[4] = { abr0, abr0 + N, abr0 + 2 * (size_t)N, abr0 + 3 * (size_t)N };

    float4v kr[4], vr[4], qr[4];
    #pragma unroll
    for (int s = 0; s < 4; ++s) qr[s] = ((const float4v*)qp)[s];
    #pragma unroll
    for (int s = 0; s < 4; ++s) kr[s] = ((const float4v*)kp)[s];
    #pragma unroll
    for (int r = 0; r < 4; ++r) vr[r] = *(const float4v*)(vp + r * D);

    // adj prefetch for tile 0 (nontemporal: stream-once, keep K/V in L2)
    float adjv[4][4];
    #pragma unroll
    for (int r = 0; r < 4; ++r)
        #pragma unroll
        for (int ct = 0; ct < 4; ++ct)
            adjv[r][ct] = __builtin_nontemporal_load(abr[r] + ct * 16);

    // stage K/V tile into LDS buffer `buf` from kr/vr registers
    auto stageKV = [&](int buf) {
        short8 a, b;
        #pragma unroll
        for (int i = 0; i < 8; ++i) a[i] = f2bf(kr[i >> 2][i & 3]);
        #pragma unroll
        for (int i = 0; i < 8; ++i) b[i] = f2bf(kr[2 + (i >> 2)][i & 3]);
        short* kd = &kBuf[buf][srow * LDK + schunk * 16];
        *(short8*)kd = a;
        *(short8*)(kd + 8) = b;
        #pragma unroll
        for (int i = 0; i < 4; ++i) {       // 4x4 register transpose of V
            short4v t;
            t[0] = f2bf(vr[0][i]); t[1] = f2bf(vr[1][i]);
            t[2] = f2bf(vr[2][i]); t[3] = f2bf(vr[3][i]);
            *(short4v*)&vtBuf[buf][(vd + i) * LDK + vkv] = t;
        }
    };

    // ---- preloop: Q (pre-scaled into base-2 softmax domain) + tile 0
    {
        constexpr float QSCALE = 0.125f * LOG2E;   // 1/sqrt(64) * log2(e)
        short8 a, b;
        #pragma unroll
        for (int i = 0; i < 8; ++i) a[i] = f2bf(qr[i >> 2][i & 3] * QSCALE);
        #pragma unroll
        for (int i = 0; i < 8; ++i) b[i] = f2bf(qr[2 + (i >> 2)][i & 3] * QSCALE);
        short* qd = &qLds[srow * LDK + schunk * 16];
        *(short8*)qd = a;
        *(short8*)(qd + 8) = b;
    }
    stageKV(0);
    __syncthreads();

    // Q A-fragments live in registers for the whole kernel
    short8 qf[2];
    #pragma unroll
    for (int kf = 0; kf < 2; ++kf)
        qf[kf] = *(const short8*)&qLds[(16 * wv + l15) * LDK + kf * 32 + l4 * 8];

    float4v Oacc[4];
    #pragma unroll
    for (int ct = 0; ct < 4; ++ct) Oacc[ct] = (float4v)(0.0f);
    float mrun[4]  = { -3.0e38f, -3.0e38f, -3.0e38f, -3.0e38f };
    float lrun[4]  = { 0.0f, 0.0f, 0.0f, 0.0f };
    float sdiag[4] = { -3.0e38f, -3.0e38f, -3.0e38f, -3.0e38f };

    #pragma unroll 2
    for (int j = 0; j < TILES; ++j) {
        const int  c    = j & 1;
        const bool last = (j + 1 == TILES);

        // issue next tile's global loads early (full-iteration latency hiding)
        if (!last) { kp += BN * D; vp += BN * D; }
        #pragma unroll
        for (int s = 0; s < 4; ++s) kr[s] = ((const float4v*)kp)[s];
        #pragma unroll
        for (int r = 0; r < 4; ++r) vr[r] = *(const float4v*)(vp + r * D);

        // ---- S = Qs * K^T  (already in base-2 domain via Q pre-scale)
        float4v s2[4];
        #pragma unroll
        for (int ct = 0; ct < 4; ++ct) {
            float4v acc = (float4v)(0.0f);
            #pragma unroll
            for (int kf = 0; kf < 2; ++kf) {
                short8 bfrag = *(const short8*)&kBuf[c][(ct * 16 + l15) * LDK + kf * 32 + l4 * 8];
                acc = __builtin_amdgcn_mfma_f32_16x16x32_bf16(qf[kf], bfrag, acc, 0, 0, 0);
            }
            s2[ct] = acc;
        }

        // add adjacency bias (times log2e), then prefetch next tile's adj
        #pragma unroll
        for (int ct = 0; ct < 4; ++ct)
            #pragma unroll
            for (int r = 0; r < 4; ++r)
                s2[ct][r] = __builtin_fmaf(adjv[r][ct], LOG2E, s2[ct][r]);
        if (!last) {
            #pragma unroll
            for (int r = 0; r < 4; ++r) abr[r] += BN;
        }
        #pragma unroll
        for (int r = 0; r < 4; ++r)
            #pragma unroll
            for (int ct = 0; ct < 4; ++ct)
                adjv[r][ct] = __builtin_nontemporal_load(abr[r] + ct * 16);

        // ---- diagonal capture (tile j == qt holds all diagonals of this WG)
        if (j == qt) {
            #pragma unroll
            for (int ct = 0; ct < 4; ++ct)
                #pragma unroll
                for (int r = 0; r < 4; ++r)
                    if (ct * 16 + l15 == rowl + r) sdiag[r] = s2[ct][r];
            #pragma unroll
            for (int r = 0; r < 4; ++r) {   // broadcast within 16-lane row group
                float t = sdiag[r];
                t = fmaxf(t, __shfl_xor(t, 1));
                t = fmaxf(t, __shfl_xor(t, 2));
                t = fmaxf(t, __shfl_xor(t, 4));
                t = fmaxf(t, __shfl_xor(t, 8));
                sdiag[r] = t;
            }
        }

        // ---- online softmax (all in C-layout registers + shuffles)
        float alr[4];
        #pragma unroll
        for (int r = 0; r < 4; ++r) {
            float t = fmaxf(fmaxf(s2[0][r], s2[1][r]), fmaxf(s2[2][r], s2[3][r]));
            t = fmaxf(t, __shfl_xor(t, 1));
            t = fmaxf(t, __shfl_xor(t, 2));
            t = fmaxf(t, __shfl_xor(t, 4));
            t = fmaxf(t, __shfl_xor(t, 8));
            float mn = fmaxf(mrun[r], t);
            alr[r]  = __builtin_amdgcn_exp2f(mrun[r] - mn);
            mrun[r] = mn;
        }
        float p[4][4];
        #pragma unroll
        for (int ct = 0; ct < 4; ++ct)
            #pragma unroll
            for (int r = 0; r < 4; ++r)
                p[ct][r] = __builtin_amdgcn_exp2f(s2[ct][r] - mrun[r]);
        #pragma unroll
        for (int r = 0; r < 4; ++r) {
            float s = (p[0][r] + p[1][r]) + (p[2][r] + p[3][r]);
            s += __shfl_xor(s, 1);
            s += __shfl_xor(s, 2);
            s += __shfl_xor(s, 4);
            s += __shfl_xor(s, 8);
            lrun[r] = __builtin_fmaf(lrun[r], alr[r], s);
        }

        // ---- P -> LDS (rows are wave-private: no barrier needed)
        #pragma unroll
        for (int ct = 0; ct < 4; ++ct)
            #pragma unroll
            for (int r = 0; r < 4; ++r)
                pLds[(rowl + r) * LDK + ct * 16 + l15] = f2bf(p[ct][r]);

        // rescale O by exp2(m_old - m_new)
        #pragma unroll
        for (int ct = 0; ct < 4; ++ct)
            #pragma unroll
            for (int r = 0; r < 4; ++r)
                Oacc[ct][r] *= alr[r];

        // ---- O += P @ V
        short8 pf0 = *(const short8*)&pLds[(16 * wv + l15) * LDK + l4 * 8];
        short8 pf1 = *(const short8*)&pLds[(16 * wv + l15) * LDK + 32 + l4 * 8];
        #pragma unroll
        for (int ct = 0; ct < 4; ++ct) {
            short8 b0 = *(const short8*)&vtBuf[c][(ct * 16 + l15) * LDK + l4 * 8];
            short8 b1 = *(const short8*)&vtBuf[c][(ct * 16 + l15) * LDK + 32 + l4 * 8];
            Oacc[ct] = __builtin_amdgcn_mfma_f32_16x16x32_bf16(pf0, b0, Oacc[ct], 0, 0, 0);
            Oacc[ct] = __builtin_amdgcn_mfma_f32_16x16x32_bf16(pf1, b1, Oacc[ct], 0, 0, 0);
        }

        // stage next tile into the other buffer; one barrier per iteration
        stageKV(c ^ 1);
        __syncthreads();
    }

    // ---- epilogue: out = beta*O/l + (alpha - beta*p_diag)*v[row]
    const float s_alpha = galpha[h];
    const float s_beta  = gbeta[h];
    const float* vrow = gv  + ((size_t)h * N + q0 + rowl) * D + l15;
    float*       op   = gout + ((size_t)h * N + q0 + rowl) * D + l15;
    #pragma unroll
    for (int r = 0; r < 4; ++r) {
        float inv  = 1.0f / lrun[r];
        float pd   = __builtin_amdgcn_exp2f(sdiag[r] - mrun[r]) * inv;
        float coef = s_alpha - s_beta * pd;
        #pragma unroll
        for (int ct = 0; ct < 4; ++ct) {
            float vvv = vrow[(size_t)r * D + ct * 16];
            op[(size_t)r * D + ct * 16] = s_beta * (Oacc[ct][r] * inv) + coef * vvv;
        }
    }
}

extern "C" void kernel_launch(void* const* d_in, const int* in_sizes, int n_in,
                              void* d_out, int out_size, void* d_ws, size_t ws_size,
                              hipStream_t stream) {
    const float* q     = (const float*)d_in[0];
    const float* k     = (const float*)d_in[1];
    const float* v     = (const float*)d_in[2];
    const float* adj   = (const float*)d_in[3];
    const float* alpha = (const float*)d_in[4];
    const float* beta  = (const float*)d_in[5];
    float* out = (float*)d_out;

    dim3 grid(NH * (N / BM));   // 512 WGs = 2 per CU
    dim3 block(256);
    attn_adj_kernel<<<grid, block, 0, stream>>>(q, k, v, adj, alpha, beta, out);
}

// Round 2
// 778.739 us; speedup vs baseline: 1.0087x; 1.0087x over previous
//
#include <hip/hip_runtime.h>

// ---------------------------------------------------------------------------
// Fused "adjacency attention":
//   out = beta*softmax(q k^T/8 + adj) @ v, diagonal of score matrix replaced
//   by alpha before PV.
// Flash-style, BM=64 q rows/WG, BN=64 kv tiles, 64 iterations.
// Round 2: adj (512 MiB stream) now fetched with contiguous dwordx4 (4 KiB
// per WG instruction) into regs -> bf16 LDS tile -> C-layout reads.
// Round 1's scalar 64B C-layout loads gave 0.68 TB/s effective HBM.
// ---------------------------------------------------------------------------

#define LOG2E 1.4426950408889634f

typedef __attribute__((ext_vector_type(8))) short  short8;   // 8 x bf16 frag
typedef __attribute__((ext_vector_type(4))) short  short4v;
typedef __attribute__((ext_vector_type(4))) float  float4v;

constexpr int NH    = 8;
constexpr int N     = 4096;
constexpr int D     = 64;
constexpr int BM    = 64;          // q rows per workgroup
constexpr int BN    = 64;          // kv per tile
constexpr int TILES = N / BN;      // 64
constexpr int LDK   = 80;          // padded LDS row stride (bf16 units), 160 B
constexpr int LDA   = 72;          // adj LDS row stride (bf16 units), 144 B

__device__ __forceinline__ short f2bf(float f) {
    unsigned u = __builtin_bit_cast(unsigned, f);
    u = (u + 0x7fffu + ((u >> 16) & 1u)) >> 16;   // RNE truncate to bf16
    return (short)u;
}
__device__ __forceinline__ float bf2f(short s) {
    unsigned u = ((unsigned)(unsigned short)s) << 16;
    return __builtin_bit_cast(float, u);
}

__global__ __launch_bounds__(256, 2)
void attn_adj_kernel(const float* __restrict__ gq, const float* __restrict__ gk,
                     const float* __restrict__ gv, const float* __restrict__ gadj,
                     const float* __restrict__ galpha, const float* __restrict__ gbeta,
                     float* __restrict__ gout)
{
    __shared__ short qLds[BM * LDK];        // 10,240 B
    __shared__ short kBuf[2][BN * LDK];     // 20,480 B
    __shared__ short vtBuf[2][D * LDK];     // 20,480 B  [d][kv]
    __shared__ short pLds[BM * LDK];        // 10,240 B  rows wave-private
    __shared__ short adjBuf[2][BM * LDA];   // 18,432 B  bf16 adj tile [row][col]

    const int tid  = threadIdx.x;
    const int lane = tid & 63;
    const int wv   = tid >> 6;      // wave 0..3 -> q rows [16*wv, 16*wv+16)
    const int l15  = lane & 15;
    const int l4   = lane >> 4;     // 0..3

    // XCD swizzle: head = bx & 7 so each XCD's resident WGs share one head's K/V.
    const int h  = blockIdx.x & 7;
    const int qt = blockIdx.x >> 3;      // 0..63
    const int q0 = qt * BM;

    // ---- staging maps (256 threads)
    const int srow   = tid >> 2;         // 0..63  (K / Q row)
    const int schunk = tid & 3;          // 16-float chunk
    const int vd     = (tid & 15) * 4;   // V: d base
    const int vkv    = (tid >> 4) * 4;   // V: kv base

    const float* qp = gq + ((size_t)h * N + q0 + srow) * D + schunk * 16;
    const float* kp = gk + ((size_t)h * N + srow) * D + schunk * 16;
    const float* vp = gv + ((size_t)h * N + vkv) * D + vd;

    const int rowl = 16 * wv + l4 * 4;   // local q row base for C-layout (+reg)

    // ---- adj contiguous-load map: load s covers tile rows [s*16, s*16+16)
    // thread t -> row s*16 + (t>>4), cols (t&15)*4 .. +3  (16B per load)
    const int arow = tid >> 4;           // 0..15
    const int acol = (tid & 15) * 4;     // 0,4,..,60
    const float* ap = gadj + ((size_t)h * N + q0 + arow) * N + acol;
    const size_t arowstep = (size_t)16 * N;   // +16 rows per load step

    float4v kr[4], vr[4], qr[4], adjr[4];
    #pragma unroll
    for (int s = 0; s < 4; ++s) qr[s] = ((const float4v*)qp)[s];
    #pragma unroll
    for (int s = 0; s < 4; ++s) kr[s] = ((const float4v*)kp)[s];
    #pragma unroll
    for (int r = 0; r < 4; ++r) vr[r] = *(const float4v*)(vp + r * D);

    // stage K/V tile into LDS buffer `buf` from kr/vr registers
    auto stageKV = [&](int buf) {
        short8 a, b;
        #pragma unroll
        for (int i = 0; i < 8; ++i) a[i] = f2bf(kr[i >> 2][i & 3]);
        #pragma unroll
        for (int i = 0; i < 8; ++i) b[i] = f2bf(kr[2 + (i >> 2)][i & 3]);
        short* kd = &kBuf[buf][srow * LDK + schunk * 16];
        *(short8*)kd = a;
        *(short8*)(kd + 8) = b;
        #pragma unroll
        for (int i = 0; i < 4; ++i) {       // 4x4 register transpose of V
            short4v t;
            t[0] = f2bf(vr[0][i]); t[1] = f2bf(vr[1][i]);
            t[2] = f2bf(vr[2][i]); t[3] = f2bf(vr[3][i]);
            *(short4v*)&vtBuf[buf][(vd + i) * LDK + vkv] = t;
        }
    };
    // write adj regs (one tile) into adjBuf[buf] as bf16
    auto stageAdj = [&](int buf) {
        #pragma unroll
        for (int s = 0; s < 4; ++s) {
            short4v t;
            #pragma unroll
            for (int i = 0; i < 4; ++i) t[i] = f2bf(adjr[s][i]);
            *(short4v*)&adjBuf[buf][(s * 16 + arow) * LDA + acol] = t;
        }
    };

    // ---- preloop: adj tile0 -> adjBuf[0]; adj tile1 -> regs (in flight)
    #pragma unroll
    for (int s = 0; s < 4; ++s)
        adjr[s] = __builtin_nontemporal_load((const float4v*)(ap + (size_t)s * arowstep));
    stageAdj(0);
    #pragma unroll
    for (int s = 0; s < 4; ++s)
        adjr[s] = __builtin_nontemporal_load((const float4v*)(ap + (size_t)s * arowstep + BN));

    // Q (pre-scaled into base-2 softmax domain) + K/V tile 0
    {
        constexpr float QSCALE = 0.125f * LOG2E;   // 1/sqrt(64) * log2(e)
        short8 a, b;
        #pragma unroll
        for (int i = 0; i < 8; ++i) a[i] = f2bf(qr[i >> 2][i & 3] * QSCALE);
        #pragma unroll
        for (int i = 0; i < 8; ++i) b[i] = f2bf(qr[2 + (i >> 2)][i & 3] * QSCALE);
        short* qd = &qLds[srow * LDK + schunk * 16];
        *(short8*)qd = a;
        *(short8*)(qd + 8) = b;
    }
    stageKV(0);
    __syncthreads();

    // Q A-fragments live in registers for the whole kernel
    short8 qf[2];
    #pragma unroll
    for (int kf = 0; kf < 2; ++kf)
        qf[kf] = *(const short8*)&qLds[(16 * wv + l15) * LDK + kf * 32 + l4 * 8];

    float4v Oacc[4];
    #pragma unroll
    for (int ct = 0; ct < 4; ++ct) Oacc[ct] = (float4v)(0.0f);
    float mrun[4]  = { -3.0e38f, -3.0e38f, -3.0e38f, -3.0e38f };
    float lrun[4]  = { 0.0f, 0.0f, 0.0f, 0.0f };
    float sdiag[4] = { -3.0e38f, -3.0e38f, -3.0e38f, -3.0e38f };

    #pragma unroll 2
    for (int j = 0; j < TILES; ++j) {
        const int  c    = j & 1;
        const bool last = (j + 1 == TILES);

        // issue next tile's K/V global loads early
        if (!last) { kp += BN * D; vp += BN * D; }
        #pragma unroll
        for (int s = 0; s < 4; ++s) kr[s] = ((const float4v*)kp)[s];
        #pragma unroll
        for (int r = 0; r < 4; ++r) vr[r] = *(const float4v*)(vp + r * D);

        // ---- S = Qs * K^T  (already in base-2 domain via Q pre-scale)
        float4v s2[4];
        #pragma unroll
        for (int ct = 0; ct < 4; ++ct) {
            float4v acc = (float4v)(0.0f);
            #pragma unroll
            for (int kf = 0; kf < 2; ++kf) {
                short8 bfrag = *(const short8*)&kBuf[c][(ct * 16 + l15) * LDK + kf * 32 + l4 * 8];
                acc = __builtin_amdgcn_mfma_f32_16x16x32_bf16(qf[kf], bfrag, acc, 0, 0, 0);
            }
            s2[ct] = acc;
        }

        // add adjacency bias (times log2e) from bf16 LDS tile (C-layout reads)
        #pragma unroll
        for (int ct = 0; ct < 4; ++ct)
            #pragma unroll
            for (int r = 0; r < 4; ++r) {
                float av = bf2f(adjBuf[c][(rowl + r) * LDA + ct * 16 + l15]);
                s2[ct][r] = __builtin_fmaf(av, LOG2E, s2[ct][r]);
            }

        // park adj regs (tile j+1) into adjBuf[c^1]; then issue loads for j+2
        stageAdj(c ^ 1);
        {
            const int   tl   = (j + 2 < TILES) ? (j + 2) : (TILES - 1);
            const float* apc = ap + (size_t)tl * BN;
            #pragma unroll
            for (int s = 0; s < 4; ++s)
                adjr[s] = __builtin_nontemporal_load((const float4v*)(apc + (size_t)s * arowstep));
        }

        // ---- diagonal capture (tile j == qt holds all diagonals of this WG)
        if (j == qt) {
            #pragma unroll
            for (int ct = 0; ct < 4; ++ct)
                #pragma unroll
                for (int r = 0; r < 4; ++r)
                    if (ct * 16 + l15 == rowl + r) sdiag[r] = s2[ct][r];
            #pragma unroll
            for (int r = 0; r < 4; ++r) {   // broadcast within 16-lane row group
                float t = sdiag[r];
                t = fmaxf(t, __shfl_xor(t, 1));
                t = fmaxf(t, __shfl_xor(t, 2));
                t = fmaxf(t, __shfl_xor(t, 4));
                t = fmaxf(t, __shfl_xor(t, 8));
                sdiag[r] = t;
            }
        }

        // ---- online softmax (C-layout registers + 16-lane shuffles)
        float alr[4];
        #pragma unroll
        for (int r = 0; r < 4; ++r) {
            float t = fmaxf(fmaxf(s2[0][r], s2[1][r]), fmaxf(s2[2][r], s2[3][r]));
            t = fmaxf(t, __shfl_xor(t, 1));
            t = fmaxf(t, __shfl_xor(t, 2));
            t = fmaxf(t, __shfl_xor(t, 4));
            t = fmaxf(t, __shfl_xor(t, 8));
            float mn = fmaxf(mrun[r], t);
            alr[r]  = __builtin_amdgcn_exp2f(mrun[r] - mn);
            mrun[r] = mn;
        }
        float p[4][4];
        #pragma unroll
        for (int ct = 0; ct < 4; ++ct)
            #pragma unroll
            for (int r = 0; r < 4; ++r)
                p[ct][r] = __builtin_amdgcn_exp2f(s2[ct][r] - mrun[r]);
        #pragma unroll
        for (int r = 0; r < 4; ++r) {
            float s = (p[0][r] + p[1][r]) + (p[2][r] + p[3][r]);
            s += __shfl_xor(s, 1);
            s += __shfl_xor(s, 2);
            s += __shfl_xor(s, 4);
            s += __shfl_xor(s, 8);
            lrun[r] = __builtin_fmaf(lrun[r], alr[r], s);
        }

        // ---- P -> LDS (rows are wave-private: no barrier needed)
        #pragma unroll
        for (int ct = 0; ct < 4; ++ct)
            #pragma unroll
            for (int r = 0; r < 4; ++r)
                pLds[(rowl + r) * LDK + ct * 16 + l15] = f2bf(p[ct][r]);

        // rescale O by exp2(m_old - m_new)
        #pragma unroll
        for (int ct = 0; ct < 4; ++ct)
            #pragma unroll
            for (int r = 0; r < 4; ++r)
                Oacc[ct][r] *= alr[r];

        // ---- O += P @ V
        short8 pf0 = *(const short8*)&pLds[(16 * wv + l15) * LDK + l4 * 8];
        short8 pf1 = *(const short8*)&pLds[(16 * wv + l15) * LDK + 32 + l4 * 8];
        #pragma unroll
        for (int ct = 0; ct < 4; ++ct) {
            short8 b0 = *(const short8*)&vtBuf[c][(ct * 16 + l15) * LDK + l4 * 8];
            short8 b1 = *(const short8*)&vtBuf[c][(ct * 16 + l15) * LDK + 32 + l4 * 8];
            Oacc[ct] = __builtin_amdgcn_mfma_f32_16x16x32_bf16(pf0, b0, Oacc[ct], 0, 0, 0);
            Oacc[ct] = __builtin_amdgcn_mfma_f32_16x16x32_bf16(pf1, b1, Oacc[ct], 0, 0, 0);
        }

        // stage next K/V tile into the other buffer; one barrier per iteration
        stageKV(c ^ 1);
        __syncthreads();
    }

    // ---- epilogue: out = beta*O/l + (alpha - beta*p_diag)*v[row]
    const float s_alpha = galpha[h];
    const float s_beta  = gbeta[h];
    const float* vrow = gv  + ((size_t)h * N + q0 + rowl) * D + l15;
    float*       op   = gout + ((size_t)h * N + q0 + rowl) * D + l15;
    #pragma unroll
    for (int r = 0; r < 4; ++r) {
        float inv  = 1.0f / lrun[r];
        float pd   = __builtin_amdgcn_exp2f(sdiag[r] - mrun[r]) * inv;
        float coef = s_alpha - s_beta * pd;
        #pragma unroll
        for (int ct = 0; ct < 4; ++ct) {
            float vvv = vrow[(size_t)r * D + ct * 16];
            op[(size_t)r * D + ct * 16] = s_beta * (Oacc[ct][r] * inv) + coef * vvv;
        }
    }
}

extern "C" void kernel_launch(void* const* d_in, const int* in_sizes, int n_in,
                              void* d_out, int out_size, void* d_ws, size_t ws_size,
                              hipStream_t stream) {
    const float* q     = (const float*)d_in[0];
    const float* k     = (const float*)d_in[1];
    const float* v     = (const float*)d_in[2];
    const float* adj   = (const float*)d_in[3];
    const float* alpha = (const float*)d_in[4];
    const float* beta  = (const float*)d_in[5];
    float* out = (float*)d_out;

    dim3 grid(NH * (N / BM));   // 512 WGs = 2 per CU
    dim3 block(256);
    attn_adj_kernel<<<grid, block, 0, stream>>>(q, k, v, adj, alpha, beta, out);
}